// Round 1
// baseline (715.897 us; speedup 1.0000x reference)
//
#include <hip/hip_runtime.h>
#include <math.h>

#define S_LEN 2048
#define DIM   1024
#define HEADS 16
#define DK    64
#define BATCH 4

typedef __bf16 bf16;
typedef bf16  bf16x8 __attribute__((ext_vector_type(8)));
typedef bf16  bf16x4 __attribute__((ext_vector_type(4)));
typedef float f32x4  __attribute__((ext_vector_type(4)));

// ---------------------------------------------------------------------------
// NT GEMM: C[M][N] = A[M][K] @ W[N][K]^T + bias[N]
// MODE 0: bf16 out, row-major [M][N]
// MODE 1: bf16 out, per-batch transposed: Vt[(row/2048)*DIM + col][row%2048]
// MODE 2: f32 out, row-major [M][N]
// 128x128 tile, BK=32, 4 waves (2x2), 4x4 16x16x32 fragments per wave.
// Reg-staged f32->bf16 conversion into +8-padded LDS (conflict-spread reads).
// ---------------------------------------------------------------------------
template<int MODE>
__global__ __launch_bounds__(256)
void gemm_nt(const float* __restrict__ A, const float* __restrict__ W,
             const float* __restrict__ bias, void* __restrict__ Cout,
             int M, int N, int K)
{
  __shared__ bf16 As[128][40];
  __shared__ bf16 Bs[128][40];
  const int tid  = threadIdx.x;
  const int lane = tid & 63, wid = tid >> 6;
  const int l15  = lane & 15, lg = lane >> 4;
  const int m0 = blockIdx.y * 128, n0 = blockIdx.x * 128;
  const int wm = wid >> 1, wn = wid & 1;

  f32x4 acc[4][4] = {};

  const int ar = tid >> 3;          // 0..31
  const int ac = (tid & 7) * 4;     // 0..28 step 4

  for (int k0 = 0; k0 < K; k0 += 32) {
    #pragma unroll
    for (int u = 0; u < 4; ++u) {
      const int r = ar + 32 * u;
      float4 av = *reinterpret_cast<const float4*>(&A[(size_t)(m0 + r) * K + k0 + ac]);
      float4 wv = *reinterpret_cast<const float4*>(&W[(size_t)(n0 + r) * K + k0 + ac]);
      bf16x4 ab, wb;
      ab[0] = (bf16)av.x; ab[1] = (bf16)av.y; ab[2] = (bf16)av.z; ab[3] = (bf16)av.w;
      wb[0] = (bf16)wv.x; wb[1] = (bf16)wv.y; wb[2] = (bf16)wv.z; wb[3] = (bf16)wv.w;
      *reinterpret_cast<bf16x4*>(&As[r][ac]) = ab;
      *reinterpret_cast<bf16x4*>(&Bs[r][ac]) = wb;
    }
    __syncthreads();
    bf16x8 af[4], bfr[4];
    #pragma unroll
    for (int i = 0; i < 4; ++i) {
      af[i]  = *reinterpret_cast<const bf16x8*>(&As[wm * 64 + i * 16 + l15][lg * 8]);
      bfr[i] = *reinterpret_cast<const bf16x8*>(&Bs[wn * 64 + i * 16 + l15][lg * 8]);
    }
    #pragma unroll
    for (int mi = 0; mi < 4; ++mi)
      #pragma unroll
      for (int ni = 0; ni < 4; ++ni)
        acc[mi][ni] = __builtin_amdgcn_mfma_f32_16x16x32_bf16(af[mi], bfr[ni], acc[mi][ni], 0, 0, 0);
    __syncthreads();
  }

  // epilogue: C row = (lane>>4)*4 + reg, col = lane&15  (m89-verified layout)
  #pragma unroll
  for (int ni = 0; ni < 4; ++ni) {
    const int col = n0 + wn * 64 + ni * 16 + l15;
    const float bi = bias[col];
    #pragma unroll
    for (int mi = 0; mi < 4; ++mi) {
      const int row0 = m0 + wm * 64 + mi * 16 + lg * 4;
      if (MODE == 0) {
        bf16* out = (bf16*)Cout;
        #pragma unroll
        for (int r = 0; r < 4; ++r)
          out[(size_t)(row0 + r) * N + col] = (bf16)(acc[mi][ni][r] + bi);
      } else if (MODE == 1) {
        bf16* out = (bf16*)Cout;
        bf16x4 vv;
        #pragma unroll
        for (int r = 0; r < 4; ++r) vv[r] = (bf16)(acc[mi][ni][r] + bi);
        *reinterpret_cast<bf16x4*>(
            &out[((size_t)(row0 >> 11) * DIM + col) * S_LEN + (row0 & (S_LEN - 1))]) = vv;
      } else {
        float* out = (float*)Cout;
        #pragma unroll
        for (int r = 0; r < 4; ++r)
          out[(size_t)(row0 + r) * N + col] = acc[mi][ni][r] + bi;
      }
    }
  }
}

// ---------------------------------------------------------------------------
// Flash attention with int mask. Block = 4 waves, 64 q-rows (16 per wave).
// K/V fragments read直接 from global (L1/L2-resident per (b,h) slice).
// P staged through per-wave padded LDS for the C-layout -> A-fragment transpose.
// ---------------------------------------------------------------------------
__global__ __launch_bounds__(256)
void attn_fwd(const bf16* __restrict__ Qb, const bf16* __restrict__ Kb,
              const bf16* __restrict__ Vt, const int* __restrict__ mask,
              float* __restrict__ ctx)
{
  __shared__ bf16 Plds[4][16][72];
  const int tid  = threadIdx.x;
  const int lane = tid & 63, wid = tid >> 6;
  const int l15  = lane & 15, lg = lane >> 4;
  const int h = blockIdx.y, b = blockIdx.z;
  const int qbase = blockIdx.x * 64 + wid * 16;

  // Q fragments: rows q = qbase + l15, k-dim d contiguous
  bf16x8 qf[2];
  {
    const size_t qrow = (size_t)b * S_LEN + qbase + l15;
    #pragma unroll
    for (int s = 0; s < 2; ++s)
      qf[s] = *reinterpret_cast<const bf16x8*>(&Qb[qrow * DIM + h * DK + s * 32 + lg * 8]);
  }

  f32x4 o[4] = {};
  float mrow[4], lrow[4];
  #pragma unroll
  for (int r = 0; r < 4; ++r) { mrow[r] = -INFINITY; lrow[r] = 0.f; }

  const int* mbase = mask + (size_t)b * S_LEN * S_LEN;

  for (int kt = 0; kt < S_LEN; kt += 64) {
    // --- QK^T: scores[16 q][64 k] in C layout (col=k=l15+16nf, row=q=lg*4+r)
    f32x4 sc[4] = {};
    #pragma unroll
    for (int nf = 0; nf < 4; ++nf) {
      const size_t krow = (size_t)b * S_LEN + kt + nf * 16 + l15;
      #pragma unroll
      for (int s = 0; s < 2; ++s) {
        bf16x8 kf = *reinterpret_cast<const bf16x8*>(&Kb[krow * DIM + h * DK + s * 32 + lg * 8]);
        sc[nf] = __builtin_amdgcn_mfma_f32_16x16x32_bf16(qf[s], kf, sc[nf], 0, 0, 0);
      }
    }
    // --- scale + mask
    #pragma unroll
    for (int nf = 0; nf < 4; ++nf) {
      const int kk = kt + nf * 16 + l15;
      #pragma unroll
      for (int r = 0; r < 4; ++r) {
        const int q = qbase + lg * 4 + r;
        const int mv = mbase[(size_t)q * S_LEN + kk];
        const float sv = sc[nf][r] * 0.125f;
        sc[nf][r] = (mv == 0) ? -1e9f : sv;
      }
    }
    // --- online softmax (row q lives on 16 lanes x 4 nf; reduce via shfl_xor<16)
    #pragma unroll
    for (int r = 0; r < 4; ++r) {
      float mx = fmaxf(fmaxf(sc[0][r], sc[1][r]), fmaxf(sc[2][r], sc[3][r]));
      #pragma unroll
      for (int d = 1; d < 16; d <<= 1) mx = fmaxf(mx, __shfl_xor(mx, d));
      const float mnew  = fmaxf(mrow[r], mx);
      const float scale = __expf(mrow[r] - mnew);   // first tile: exp(-inf)=0
      mrow[r] = mnew;
      float ps = 0.f;
      #pragma unroll
      for (int nf = 0; nf < 4; ++nf) {
        const float p = __expf(sc[nf][r] - mnew);
        sc[nf][r] = p;
        ps += p;
      }
      #pragma unroll
      for (int d = 1; d < 16; d <<= 1) ps += __shfl_xor(ps, d);
      lrow[r] = lrow[r] * scale + ps;
      #pragma unroll
      for (int nf = 0; nf < 4; ++nf) o[nf][r] *= scale;
    }
    // --- P -> LDS (per-wave private, padded stride 72)
    #pragma unroll
    for (int nf = 0; nf < 4; ++nf)
      #pragma unroll
      for (int r = 0; r < 4; ++r)
        Plds[wid][lg * 4 + r][nf * 16 + l15] = (bf16)sc[nf][r];
    __syncthreads();
    // --- PV: A = P rows (q=l15, k contig from LDS), B = Vt rows (d=l15+16nf)
    #pragma unroll
    for (int s = 0; s < 2; ++s) {
      bf16x8 pf = *reinterpret_cast<const bf16x8*>(&Plds[wid][l15][s * 32 + lg * 8]);
      #pragma unroll
      for (int nf = 0; nf < 4; ++nf) {
        bf16x8 vf = *reinterpret_cast<const bf16x8*>(
            &Vt[((size_t)b * DIM + h * DK + nf * 16 + l15) * S_LEN + kt + s * 32 + lg * 8]);
        o[nf] = __builtin_amdgcn_mfma_f32_16x16x32_bf16(pf, vf, o[nf], 0, 0, 0);
      }
    }
    __syncthreads();
  }

  // --- epilogue: ctx[b][q][h*64+d] = o / l
  #pragma unroll
  for (int nf = 0; nf < 4; ++nf) {
    #pragma unroll
    for (int r = 0; r < 4; ++r) {
      const int q = qbase + lg * 4 + r;
      ctx[((size_t)b * S_LEN + q) * DIM + h * DK + nf * 16 + l15] = o[nf][r] / lrow[r];
    }
  }
}

// ---------------------------------------------------------------------------
extern "C" void kernel_launch(void* const* d_in, const int* in_sizes, int n_in,
                              void* d_out, int out_size, void* d_ws, size_t ws_size,
                              hipStream_t stream)
{
  const float* q    = (const float*)d_in[0];
  const float* k    = (const float*)d_in[1];
  const float* v    = (const float*)d_in[2];
  const int*   mask = (const int*)  d_in[3];
  const float* Wq   = (const float*)d_in[4];
  const float* bq   = (const float*)d_in[5];
  const float* Wk   = (const float*)d_in[6];
  const float* bk   = (const float*)d_in[7];
  const float* Wv   = (const float*)d_in[8];
  const float* bv   = (const float*)d_in[9];
  const float* Wo   = (const float*)d_in[10];
  const float* bo   = (const float*)d_in[11];
  float* out = (float*)d_out;

  const size_t NE = (size_t)BATCH * S_LEN * DIM;  // 8.39M
  bf16* Qb = (bf16*)d_ws;
  bf16* Kb = Qb + NE;
  bf16* Vt = Kb + NE;
  float* ctx = (float*)(Vt + NE);

  const int M = BATCH * S_LEN;  // 8192
  dim3 gg(DIM / 128, M / 128);  // (8, 64)

  gemm_nt<0><<<gg, 256, 0, stream>>>(q, Wq, bq, Qb, M, DIM, DIM);
  gemm_nt<0><<<gg, 256, 0, stream>>>(k, Wk, bk, Kb, M, DIM, DIM);
  gemm_nt<1><<<gg, 256, 0, stream>>>(v, Wv, bv, Vt, M, DIM, DIM);

  attn_fwd<<<dim3(S_LEN / 64, HEADS, BATCH), 256, 0, stream>>>(Qb, Kb, Vt, mask, ctx);

  gemm_nt<2><<<gg, 256, 0, stream>>>(ctx, Wo, bo, out, M, DIM, DIM);
}